// Round 3
// baseline (1057.545 us; speedup 1.0000x reference)
//
#include <hip/hip_runtime.h>
#include <math.h>

// VQ-VAE forward on MI355X (gfx950).
// z: (16,256,64,64) f32 ; emb: (1024,256) f32
// Outputs flat f32: z_q(16.7M) | loss | perp | one_hot(67.1M) | idx(65536) | d(67.1M)
//
// Round-3: bf16 MFMA distance GEMM (dot = z_hi*(e_hi+e_lo), K'=512) + top-2 flag +
// exact-f32-chain refine for near-tie rows (reproduces round-2's validated argmin).

typedef unsigned short ushort;
typedef unsigned int uint;
typedef __attribute__((ext_vector_type(8))) short  bf16x8;
typedef __attribute__((ext_vector_type(8))) ushort ushort8v;
typedef __attribute__((ext_vector_type(4))) float  f32x4;

static const size_t O_LOSS = 16777216;
static const size_t O_PERP = 16777217;
static const size_t O_OH   = 16777218;
static const size_t O_IDX  = 83886082;
static const size_t O_D    = 83951618;

// ---- new-path ws layout (bytes) ----
static const size_t WS_ENORM = 0;          // f32[1024]
static const size_t WS_ZNF   = 4096;       // f32[65536]
static const size_t WS_IDX   = 266240;     // i32[65536]
static const size_t WS_HIST  = 528384;     // i32[1024]
static const size_t WS_FCNT  = 532480;     // i32 (+pad)
static const size_t WS_FROWS = 532496;     // i32[65536]
static const size_t WS_LOSS  = 794640;     // f64[1024]
static const size_t WS_TOP2  = 802832;     // float4[65536*8]  (8 MB)
static const size_t WS_AHI   = 9191440;    // bf16[65536*256]  (32 MB)
static const size_t WS_BHL   = 42745872;   // bf16[1024*512]   (1 MB)
static const size_t WS_NEEDED = 43794448;

#define THR_FLAG 5e-4f

__device__ __forceinline__ ushort f2bf(float f) {
  uint u = __float_as_uint(f);
  return (ushort)((u + 0x7FFFu + ((u >> 16) & 1u)) >> 16);   // RNE
}
__device__ __forceinline__ float bf2f(ushort h) {
  return __uint_as_float(((uint)h) << 16);
}
__device__ __forceinline__ void gload16(const void* g, void* l) {
  __builtin_amdgcn_global_load_lds(
      (const __attribute__((address_space(1))) void*)g,
      (__attribute__((address_space(3))) void*)l, 16, 0, 0);
}

// ---------- prep: emb -> enormf(f64 seq, round once) + B' = [e_hi | e_lo] ----------
__global__ __launch_bounds__(256) void vq_prep_e(const float* __restrict__ emb,
    float* __restrict__ enormf, ushort* __restrict__ Bhl) {
  const int j = blockIdx.x * 256 + threadIdx.x;
  const float* e = emb + ((size_t)j << 8);
  ushort* br = Bhl + ((size_t)j << 9);
  double s = 0.0;
  for (int k = 0; k < 256; ++k) {
    const float v = e[k];
    const double dv = (double)v; s += dv * dv;
    const ushort h = f2bf(v);
    br[k] = h;
    br[256 + k] = f2bf(v - bf2f(h));
  }
  enormf[j] = (float)s;
}

// ---------- prep: z -> A' = bf16(z) row-major [m][256], znf (f64, round once) ----------
__global__ __launch_bounds__(256) void vq_prep_z(const float* __restrict__ z,
    ushort* __restrict__ Ahi, float* __restrict__ znf) {
  __shared__ float As[256][68];
  __shared__ double znp[64][4];
  const int t = threadIdx.x;
  const int lane = t & 63, quad = t >> 6;
  const int blk = blockIdx.x;
  const float* zb = z + (((size_t)(blk >> 6)) << 20) + (((size_t)(blk & 63)) << 6);
  {
    const int kr = t >> 4, xc = (t & 15) << 2;
    for (int k0 = 0; k0 < 256; k0 += 16) {
      const int k = k0 + kr;
      *(float4*)&As[k][xc] = *(const float4*)&zb[((size_t)k << 12) + xc];
    }
  }
  __syncthreads();
  {
    double s = 0.0;
    const int kb = quad << 6;
    for (int k = 0; k < 64; ++k) { const double v = (double)As[kb + k][lane]; s += v * v; }
    znp[lane][quad] = s;
  }
  __syncthreads();
  const int m0 = ((blk >> 6) << 12) + ((blk & 63) << 6);
  if (t < 64) znf[m0 + t] = (float)(znp[t][0] + znp[t][1] + znp[t][2] + znp[t][3]);
  const int row = t >> 2;
  ushort* dst = Ahi + ((size_t)(m0 + row) << 8);
  for (int s = 0; s < 8; ++s) {
    const int k0 = ((t & 3) + (s << 2)) << 3;
    ushort8v v;
#pragma unroll
    for (int i = 0; i < 8; ++i) v[i] = f2bf(As[k0 + i][row]);
    *(ushort8v*)&dst[k0] = v;
  }
}

// ---------- main: 128x128 bf16 MFMA GEMM (K'=512) + d store + per-block top-2 ----------
__global__ __launch_bounds__(256) void vq_gemm(const ushort* __restrict__ Ahi,
    const ushort* __restrict__ Bhl, const float* __restrict__ znf,
    const float* __restrict__ enormf, float* __restrict__ dmat,
    float4* __restrict__ top2) {
  __shared__ ushort As[128 * 32];
  __shared__ ushort Bs[128 * 32];

  const int t = threadIdx.x;
  const int lane = t & 63;
  const int w = t >> 6;
  const int wr = w >> 1, wc = w & 1;
  const int g = lane >> 4, c = lane & 15;
  const int m0 = blockIdx.x << 7;
  const int n0 = blockIdx.y << 7;

  f32x4 acc[4][4];
#pragma unroll
  for (int a = 0; a < 4; ++a)
#pragma unroll
    for (int b = 0; b < 4; ++b) acc[a][b] = (f32x4)(0.0f);

  // staging slot geometry: slot s in [0,512): row=s>>2, 8-ushort group s&3
  const int s0 = t, s1 = 256 + t;
  const int rA0 = s0 >> 2, cA0 = (s0 & 3) << 3;
  const int rA1 = s1 >> 2, cA1 = (s1 & 3) << 3;

  for (int kt = 0; kt < 16; ++kt) {
    const int kc = kt << 5;
    const int kA = kc & 255;
    __syncthreads();
    gload16(Ahi + ((size_t)(m0 + rA0) << 8) + kA + cA0, &As[s0 << 3]);
    gload16(Ahi + ((size_t)(m0 + rA1) << 8) + kA + cA1, &As[s1 << 3]);
    gload16(Bhl + ((size_t)(n0 + rA0) << 9) + kc + cA0, &Bs[s0 << 3]);
    gload16(Bhl + ((size_t)(n0 + rA1) << 9) + kc + cA1, &Bs[s1 << 3]);
    __syncthreads();
    bf16x8 av[4], bv[4];
#pragma unroll
    for (int ai = 0; ai < 4; ++ai)
      av[ai] = *(const bf16x8*)&As[((wr << 6) + (ai << 4) + c) * 32 + (g << 3)];
#pragma unroll
    for (int bj = 0; bj < 4; ++bj)
      bv[bj] = *(const bf16x8*)&Bs[((wc << 6) + (bj << 4) + c) * 32 + (g << 3)];
#pragma unroll
    for (int ai = 0; ai < 4; ++ai)
#pragma unroll
      for (int bj = 0; bj < 4; ++bj)
        acc[ai][bj] = __builtin_amdgcn_mfma_f32_16x16x32_bf16(av[ai], bv[bj], acc[ai][bj], 0, 0, 0);
  }

  // epilogue: d = znf[m] + enormf[n] - 2*acc ; store d ; per-row top-2
  __syncthreads();
  float* sd1 = (float*)As;          // [128][2]
  int*   si1 = (int*)(sd1 + 256);
  float* sd2 = (float*)(si1 + 256);

  float zn_[4][4];
#pragma unroll
  for (int ai = 0; ai < 4; ++ai)
#pragma unroll
    for (int rg = 0; rg < 4; ++rg)
      zn_[ai][rg] = znf[m0 + (wr << 6) + (ai << 4) + (g << 2) + rg];
  float en_[4];
#pragma unroll
  for (int bj = 0; bj < 4; ++bj)
    en_[bj] = enormf[n0 + (wc << 6) + (bj << 4) + c];

#pragma unroll
  for (int ai = 0; ai < 4; ++ai) {
#pragma unroll
    for (int rg = 0; rg < 4; ++rg) {
      const int m = m0 + (wr << 6) + (ai << 4) + (g << 2) + rg;
      const float zr = zn_[ai][rg];
      float m1 = 3.0e38f, m2 = 3.0e38f; int i1 = 0;
#pragma unroll
      for (int bj = 0; bj < 4; ++bj) {
        const float S = zr + en_[bj];
        const float v = S - 2.0f * acc[ai][bj][rg];
        const int n = n0 + (wc << 6) + (bj << 4) + c;
        dmat[((size_t)m << 10) + n] = v;
        if (v < m1) { m2 = m1; m1 = v; i1 = n; }
        else if (v < m2) { m2 = v; }
      }
      // top-2 merge across the 16 lanes sharing this m
#pragma unroll
      for (int off = 8; off >= 1; off >>= 1) {
        const float o1 = __shfl_xor(m1, off, 16);
        const int   oi = __shfl_xor(i1, off, 16);
        const float o2 = __shfl_xor(m2, off, 16);
        const float ns = fminf(fminf(m2, o2), fmaxf(m1, o1));
        if (o1 < m1 || (o1 == m1 && oi < i1)) { m1 = o1; i1 = oi; }
        m2 = ns;
      }
      if (c == 0) {
        const int r = (wr << 6) + (ai << 4) + (g << 2) + rg;
        sd1[(r << 1) + wc] = m1; si1[(r << 1) + wc] = i1; sd2[(r << 1) + wc] = m2;
      }
    }
  }
  __syncthreads();
  if (t < 128) {
    const float a1 = sd1[t << 1], b1 = sd1[(t << 1) + 1];
    const int ai1 = si1[t << 1], bi1 = si1[(t << 1) + 1];
    const float a2 = sd2[t << 1], b2 = sd2[(t << 1) + 1];
    float d1, d2; int i1;
    if (b1 < a1 || (b1 == a1 && bi1 < ai1)) { d1 = b1; i1 = bi1; d2 = fminf(a1, b2); }
    else { d1 = a1; i1 = ai1; d2 = fminf(b1, a2); }
    float4 r; r.x = d1; r.y = __int_as_float(i1); r.z = d2; r.w = 0.0f;
    top2[(((size_t)(m0 + t)) << 3) + blockIdx.y] = r;
  }
}

// ---------- merge 8 per-block top-2s -> global top-2, flag near-ties ----------
__global__ __launch_bounds__(256) void vq_top2merge(const float4* __restrict__ top2,
    int* __restrict__ idxw, int* __restrict__ flag_cnt, int* __restrict__ flag_rows) {
  const int row = blockIdx.x * 256 + threadIdx.x;
  const float4* tp = top2 + ((size_t)row << 3);
  float4 e = tp[0];
  float d1 = e.x; int i1 = __float_as_int(e.y); float d2 = e.z;
  for (int k = 1; k < 8; ++k) {
    e = tp[k];
    const int ei = __float_as_int(e.y);
    if (e.x < d1 || (e.x == d1 && ei < i1)) { d2 = fminf(d1, e.z); d1 = e.x; i1 = ei; }
    else { d2 = fminf(d2, fminf(e.x, e.z)); }
  }
  idxw[row] = i1;
  if (d2 - d1 < THR_FLAG) {
    const int p = atomicAdd(flag_cnt, 1);
    flag_rows[p] = row;
  }
}

// ---------- exact f32-chain re-argmin for flagged rows (bit-matches round-2 path) ----------
__global__ __launch_bounds__(256) void vq_refine(const float* __restrict__ z,
    const float* __restrict__ emb, const float* __restrict__ znf,
    const float* __restrict__ enormf, const int* __restrict__ flag_cnt,
    const int* __restrict__ flag_rows, int* __restrict__ idxw) {
  __shared__ float zrow[256];
  __shared__ float rv[256];
  __shared__ int ri[256];
  const int t = threadIdx.x;
  const int n = *flag_cnt;
  for (int f = blockIdx.x; f < n; f += 1024) {
    const int m = flag_rows[f];
    const size_t zo = (((size_t)(m >> 12)) << 20) + (size_t)(m & 4095);
    __syncthreads();
    zrow[t] = z[zo + ((size_t)t << 12)];
    __syncthreads();
    const float znr = znf[m];
    float best = 3.0e38f; int bi = 0;
    for (int q = 0; q < 4; ++q) {
      const int j = (t << 2) + q;
      const float* er = emb + ((size_t)j << 8);
      float s = 0.0f;
      for (int k = 0; k < 256; ++k) s = fmaf(zrow[k], er[k], s);
      const float S = znr + enormf[j];
      const float tv = S - 2.0f * s;
      if (tv < best || (tv == best && j < bi)) { best = tv; bi = j; }
    }
    rv[t] = best; ri[t] = bi;
    __syncthreads();
    for (int off = 128; off > 0; off >>= 1) {
      if (t < off) {
        const float ov = rv[t + off]; const int oi = ri[t + off];
        if (ov < rv[t] || (ov == rv[t] && oi < ri[t])) { rv[t] = ov; ri[t] = oi; }
      }
      __syncthreads();
    }
    if (t == 0) idxw[m] = ri[0];
  }
}

// ================= round-2 fallback dist kernel (proven) =================
__global__ __launch_bounds__(256) void vq_enorm_old(const float* __restrict__ emb,
                                                    float* __restrict__ enormf) {
  const int j = blockIdx.x * 256 + threadIdx.x;
  const float* e = emb + ((size_t)j << 8);
  double s = 0.0;
  for (int k = 0; k < 256; ++k) { const double v = (double)e[k]; s += v * v; }
  enormf[j] = (float)s;
}

__global__ __launch_bounds__(256) void vq_dist_old(const float* __restrict__ z,
    const float* __restrict__ emb, const float* __restrict__ enormf,
    float* __restrict__ dmat, int* __restrict__ idxw) {
  __shared__ float As[256][68];
  __shared__ float Bs[32][68];
  __shared__ float znf[64];
  const int t = threadIdx.x;
  const int lane = t & 63;
  const int quad = t >> 6;
  const int blk = blockIdx.x;
  const int base = blk << 6;
  const float* zb = z + (((size_t)(blk >> 6)) << 20) + (((size_t)(blk & 63)) << 6);
  {
    const int kr = t >> 4;
    const int xc = (t & 15) << 2;
    for (int k0 = 0; k0 < 256; k0 += 16) {
      const int k = k0 + kr;
      const float4 v = *(const float4*)&zb[((size_t)k << 12) + xc];
      *(float4*)&As[k][xc] = v;
    }
  }
  __syncthreads();
  {
    double* znp = (double*)&Bs[0][0];
    double s = 0.0;
    const int kb = quad << 6;
    for (int k = 0; k < 64; ++k) { const double v = (double)As[kb + k][lane]; s += v * v; }
    znp[(lane << 2) + quad] = s;
    __syncthreads();
    if (t < 64) {
      const double* zp = znp + (t << 2);
      znf[t] = (float)(zp[0] + zp[1] + zp[2] + zp[3]);
    }
  }
  const int tj = t & 15;
  const int tm = t >> 4;
  float m1[4]; int i1[4];
#pragma unroll
  for (int mm = 0; mm < 4; ++mm) { m1[mm] = 3.0e38f; i1[mm] = 0; }
  for (int jt = 0; jt < 16; ++jt) {
    const int j0 = jt << 6;
    float acc[4][4];
#pragma unroll
    for (int a = 0; a < 4; ++a)
#pragma unroll
      for (int q = 0; q < 4; ++q) acc[a][q] = 0.0f;
    for (int kc = 0; kc < 256; kc += 32) {
      __syncthreads();
#pragma unroll
      for (int i = 0; i < 8; ++i) {
        const int jl = (i << 3) + (t >> 5);
        const int kl = t & 31;
        Bs[kl][jl] = emb[(((size_t)(j0 + jl)) << 8) + kc + kl];
      }
      __syncthreads();
#pragma unroll
      for (int k2 = 0; k2 < 32; ++k2) {
        const float4 av = *(const float4*)&As[kc + k2][tm << 2];
        const float4 bv = *(const float4*)&Bs[k2][tj << 2];
        acc[0][0] = fmaf(av.x, bv.x, acc[0][0]);
        acc[0][1] = fmaf(av.x, bv.y, acc[0][1]);
        acc[0][2] = fmaf(av.x, bv.z, acc[0][2]);
        acc[0][3] = fmaf(av.x, bv.w, acc[0][3]);
        acc[1][0] = fmaf(av.y, bv.x, acc[1][0]);
        acc[1][1] = fmaf(av.y, bv.y, acc[1][1]);
        acc[1][2] = fmaf(av.y, bv.z, acc[1][2]);
        acc[1][3] = fmaf(av.y, bv.w, acc[1][3]);
        acc[2][0] = fmaf(av.z, bv.x, acc[2][0]);
        acc[2][1] = fmaf(av.z, bv.y, acc[2][1]);
        acc[2][2] = fmaf(av.z, bv.z, acc[2][2]);
        acc[2][3] = fmaf(av.z, bv.w, acc[2][3]);
        acc[3][0] = fmaf(av.w, bv.x, acc[3][0]);
        acc[3][1] = fmaf(av.w, bv.y, acc[3][1]);
        acc[3][2] = fmaf(av.w, bv.z, acc[3][2]);
        acc[3][3] = fmaf(av.w, bv.w, acc[3][3]);
      }
    }
    float ej[4];
#pragma unroll
    for (int q = 0; q < 4; ++q) ej[q] = enormf[j0 + (tj << 2) + q];
#pragma unroll
    for (int mm = 0; mm < 4; ++mm) {
      const int row = (tm << 2) + mm;
      const float zr = znf[row];
      float qv[4];
#pragma unroll
      for (int q = 0; q < 4; ++q) {
        const float S = zr + ej[q];
        qv[q] = S - 2.0f * acc[mm][q];
      }
      float2* dst = (float2*)&dmat[((size_t)(base + row) << 10) + j0 + (tj << 2)];
      dst[0] = make_float2(qv[0], qv[1]);
      dst[1] = make_float2(qv[2], qv[3]);
#pragma unroll
      for (int q = 0; q < 4; ++q) {
        const float v = qv[q];
        if (v < m1[mm]) { m1[mm] = v; i1[mm] = j0 + (tj << 2) + q; }
      }
    }
  }
#pragma unroll
  for (int mm = 0; mm < 4; ++mm) {
    float a1 = m1[mm]; int ai = i1[mm];
    for (int off = 8; off >= 1; off >>= 1) {
      const float o1 = __shfl_xor(a1, off, 16);
      const int   oi = __shfl_xor(ai, off, 16);
      if (o1 < a1 || (o1 == a1 && oi < ai)) { a1 = o1; ai = oi; }
    }
    if (tj == 0) idxw[base + (tm << 2) + mm] = ai;
  }
}

// ================= shared tail kernels =================
__global__ __launch_bounds__(256) void vq_zq(const float* __restrict__ z,
    const float* __restrict__ emb, const int* __restrict__ idxw,
    float* __restrict__ zq, double* __restrict__ loss_part) {
  __shared__ float E[64][258];
  __shared__ int il[64];
  __shared__ double red[256];
  const int t = threadIdx.x;
  const int blk = blockIdx.x;
  const int base = blk << 6;
  if (t < 64) il[t] = idxw[base + t];
  __syncthreads();
  for (int i = 0; i < 64; ++i) E[i][t] = emb[((size_t)il[i] << 8) + t];
  __syncthreads();
  const int w = t & 63, cg = t >> 6;
  const size_t zbase = (((size_t)(blk >> 6)) << 20) + (((size_t)(blk & 63)) << 6) + (size_t)w;
  double ls = 0.0;
  for (int ci = 0; ci < 64; ++ci) {
    const int c = (ci << 2) + cg;
    const float e = E[w][c];
    const size_t o = zbase + ((size_t)c << 12);
    const float zv = z[o];
    zq[o] = e;
    const double dd = (double)e - (double)zv;
    ls += dd * dd;
  }
  red[t] = ls;
  __syncthreads();
  for (int off = 128; off > 0; off >>= 1) {
    if (t < off) red[t] += red[t + off];
    __syncthreads();
  }
  if (t == 0) loss_part[blk] = red[0];
}

__global__ __launch_bounds__(256) void vq_scatter(const int* __restrict__ idxw,
    float* __restrict__ out, int* __restrict__ hist) {
  const int m = blockIdx.x * 256 + threadIdx.x;
  const int idx = idxw[m];
  out[O_OH + ((size_t)m << 10) + (size_t)idx] = 1.0f;
  out[O_IDX + (size_t)m] = (float)idx;
  atomicAdd(&hist[idx], 1);
}

__global__ __launch_bounds__(256) void vq_final(const double* __restrict__ loss_part,
    const int* __restrict__ hist, float* __restrict__ out) {
  __shared__ double red[256];
  const int t = threadIdx.x;
  double s = 0.0;
  for (int i = t; i < 1024; i += 256) s += loss_part[i];
  red[t] = s;
  __syncthreads();
  for (int off = 128; off > 0; off >>= 1) {
    if (t < off) red[t] += red[t + off];
    __syncthreads();
  }
  if (t == 0) out[O_LOSS] = (float)(1.25 * red[0] / 16777216.0);
  __syncthreads();
  double h = 0.0;
  for (int i = t; i < 1024; i += 256) {
    const double p = (double)hist[i] / 65536.0;
    h += p * log(p + 1e-10);
  }
  red[t] = h;
  __syncthreads();
  for (int off = 128; off > 0; off >>= 1) {
    if (t < off) red[t] += red[t + off];
    __syncthreads();
  }
  if (t == 0) out[O_PERP] = (float)exp(-red[0]);
}

extern "C" void kernel_launch(void* const* d_in, const int* in_sizes, int n_in,
                              void* d_out, int out_size, void* d_ws, size_t ws_size,
                              hipStream_t stream) {
  const float* z   = (const float*)d_in[0];
  const float* emb = (const float*)d_in[1];
  float* out = (float*)d_out;
  char* ws = (char*)d_ws;

  if (ws_size >= WS_NEEDED) {
    float*  enormf    = (float*)(ws + WS_ENORM);
    float*  znf       = (float*)(ws + WS_ZNF);
    int*    idxw      = (int*)(ws + WS_IDX);
    int*    hist      = (int*)(ws + WS_HIST);
    int*    flag_cnt  = (int*)(ws + WS_FCNT);
    int*    flag_rows = (int*)(ws + WS_FROWS);
    double* loss_part = (double*)(ws + WS_LOSS);
    float4* top2      = (float4*)(ws + WS_TOP2);
    ushort* Ahi       = (ushort*)(ws + WS_AHI);
    ushort* Bhl       = (ushort*)(ws + WS_BHL);

    vq_prep_e<<<4, 256, 0, stream>>>(emb, enormf, Bhl);
    vq_prep_z<<<1024, 256, 0, stream>>>(z, Ahi, znf);
    hipMemsetAsync(ws + WS_HIST, 0, 4112, stream);            // hist + flag_cnt
    hipMemsetAsync((char*)d_out + O_OH * sizeof(float), 0,
                   (size_t)67108864 * sizeof(float), stream); // one_hot zeros
    dim3 g(512, 8);
    vq_gemm<<<g, 256, 0, stream>>>(Ahi, Bhl, znf, enormf, out + O_D, top2);
    vq_top2merge<<<256, 256, 0, stream>>>(top2, idxw, flag_cnt, flag_rows);
    vq_refine<<<1024, 256, 0, stream>>>(z, emb, znf, enormf, flag_cnt, flag_rows, idxw);
    vq_zq<<<1024, 256, 0, stream>>>(z, emb, idxw, out, loss_part);
    vq_scatter<<<256, 256, 0, stream>>>(idxw, out, hist);
    vq_final<<<1, 256, 0, stream>>>(loss_part, hist, out);
  } else {
    // proven round-2 path
    float*  enormf    = (float*)(ws + 0);
    int*    idxw      = (int*)(ws + 4096);
    int*    hist      = (int*)(ws + 266240);
    double* loss_part = (double*)(ws + 270336);

    vq_enorm_old<<<4, 256, 0, stream>>>(emb, enormf);
    hipMemsetAsync(ws + 266240, 0, 4096, stream);
    hipMemsetAsync((char*)d_out + O_OH * sizeof(float), 0,
                   (size_t)67108864 * sizeof(float), stream);
    vq_dist_old<<<1024, 256, 0, stream>>>(z, emb, enormf, out + O_D, idxw);
    vq_zq<<<1024, 256, 0, stream>>>(z, emb, idxw, out, loss_part);
    vq_scatter<<<256, 256, 0, stream>>>(idxw, out, hist);
    vq_final<<<1, 256, 0, stream>>>(loss_part, hist, out);
  }
}

// Round 4
// 415.217 us; speedup vs baseline: 2.5470x; 2.5470x over previous
//
#include <hip/hip_runtime.h>
#include <math.h>

// VQ-VAE forward on MI355X (gfx950).
// z: (16,256,64,64) f32 ; emb: (1024,256) f32
// Outputs flat f32: z_q(16.7M) | loss | perp | one_hot(67.1M) | idx(65536) | d(67.1M)
//
// Round-4: bf16 MFMA distance GEMM (dot ~= bf16(z)*bf16(e), K=256) + top-2 flag
// (THR=4e-4 ~ 9.5 sigma of approx error) + CANDIDATE-based exact-f32-chain refine
// (reads stored d row, recomputes only codes within THR of row min).

typedef unsigned short ushort;
typedef unsigned int uint;
typedef __attribute__((ext_vector_type(8))) short  bf16x8;
typedef __attribute__((ext_vector_type(8))) ushort ushort8v;
typedef __attribute__((ext_vector_type(4))) float  f32x4;

static const size_t O_LOSS = 16777216;
static const size_t O_PERP = 16777217;
static const size_t O_OH   = 16777218;
static const size_t O_IDX  = 83886082;
static const size_t O_D    = 83951618;   // byte off 8 mod 16 -> float2 access only

// ---- ws layout (bytes) ----
static const size_t WS_ENORM = 0;          // f32[1024]
static const size_t WS_ZNF   = 4096;       // f32[65536]
static const size_t WS_IDX   = 266240;     // i32[65536]
static const size_t WS_HIST  = 528384;     // i32[1024]
static const size_t WS_FCNT  = 532480;     // i32 (+pad)
static const size_t WS_FROWS = 532496;     // i32[65536]
static const size_t WS_LOSS  = 794640;     // f64[1024]
static const size_t WS_TOP2  = 802832;     // float4[65536*8]  (8 MB)
static const size_t WS_AHI   = 9191440;    // bf16[65536*256]  (32 MB)
static const size_t WS_BHI   = 42745872;   // bf16[1024*256]   (512 KB)
static const size_t WS_NEEDED = 43270160;

#define THR_FLAG 4e-4f

__device__ __forceinline__ ushort f2bf(float f) {
  uint u = __float_as_uint(f);
  return (ushort)((u + 0x7FFFu + ((u >> 16) & 1u)) >> 16);   // RNE
}
__device__ __forceinline__ void gload16(const void* g, void* l) {
  __builtin_amdgcn_global_load_lds(
      (const __attribute__((address_space(1))) void*)g,
      (__attribute__((address_space(3))) void*)l, 16, 0, 0);
}

// ---------- prep: emb -> enormf (f64 seq, round once) + B = bf16(emb) ----------
__global__ __launch_bounds__(256) void vq_prep_e(const float* __restrict__ emb,
    float* __restrict__ enormf, ushort* __restrict__ Bhi) {
  const int j = blockIdx.x * 256 + threadIdx.x;
  const float* e = emb + ((size_t)j << 8);
  ushort* br = Bhi + ((size_t)j << 8);
  double s = 0.0;
  for (int k = 0; k < 256; ++k) {
    const float v = e[k];
    const double dv = (double)v; s += dv * dv;
    br[k] = f2bf(v);
  }
  enormf[j] = (float)s;
}

// ---------- prep: z -> A = bf16(z) row-major [m][256], znf (f64, round once) ----------
__global__ __launch_bounds__(256) void vq_prep_z(const float* __restrict__ z,
    ushort* __restrict__ Ahi, float* __restrict__ znf) {
  __shared__ float As[256][68];
  __shared__ double znp[64][4];
  const int t = threadIdx.x;
  const int lane = t & 63, quad = t >> 6;
  const int blk = blockIdx.x;
  const float* zb = z + (((size_t)(blk >> 6)) << 20) + (((size_t)(blk & 63)) << 6);
  {
    const int kr = t >> 4, xc = (t & 15) << 2;
    for (int k0 = 0; k0 < 256; k0 += 16) {
      const int k = k0 + kr;
      *(float4*)&As[k][xc] = *(const float4*)&zb[((size_t)k << 12) + xc];
    }
  }
  __syncthreads();
  {
    double s = 0.0;
    const int kb = quad << 6;
    for (int k = 0; k < 64; ++k) { const double v = (double)As[kb + k][lane]; s += v * v; }
    znp[lane][quad] = s;
  }
  __syncthreads();
  const int m0 = ((blk >> 6) << 12) + ((blk & 63) << 6);
  if (t < 64) znf[m0 + t] = (float)(znp[t][0] + znp[t][1] + znp[t][2] + znp[t][3]);
  const int row = t >> 2;
  ushort* dst = Ahi + ((size_t)(m0 + row) << 8);
  for (int s = 0; s < 8; ++s) {
    const int k0 = ((t & 3) + (s << 2)) << 3;
    ushort8v v;
#pragma unroll
    for (int i = 0; i < 8; ++i) v[i] = f2bf(As[k0 + i][row]);
    *(ushort8v*)&dst[k0] = v;
  }
}

// ---------- main: 128x128 bf16 MFMA GEMM (K=256) + d store + per-block top-2 ----------
__global__ __launch_bounds__(256) void vq_gemm(const ushort* __restrict__ Ahi,
    const ushort* __restrict__ Bhi, const float* __restrict__ znf,
    const float* __restrict__ enormf, float* __restrict__ dmat,
    float4* __restrict__ top2) {
  __shared__ ushort As[128 * 32];
  __shared__ ushort Bs[128 * 32];

  const int t = threadIdx.x;
  const int lane = t & 63;
  const int w = t >> 6;
  const int wr = w >> 1, wc = w & 1;
  const int g = lane >> 4, c = lane & 15;
  const int m0 = blockIdx.x << 7;
  const int n0 = blockIdx.y << 7;

  f32x4 acc[4][4];
#pragma unroll
  for (int a = 0; a < 4; ++a)
#pragma unroll
    for (int b = 0; b < 4; ++b) acc[a][b] = (f32x4)(0.0f);

  const int s0 = t, s1 = 256 + t;
  const int rA0 = s0 >> 2, cA0 = (s0 & 3) << 3;
  const int rA1 = s1 >> 2, cA1 = (s1 & 3) << 3;

  for (int kt = 0; kt < 8; ++kt) {
    const int kc = kt << 5;
    __syncthreads();
    gload16(Ahi + ((size_t)(m0 + rA0) << 8) + kc + cA0, &As[s0 << 3]);
    gload16(Ahi + ((size_t)(m0 + rA1) << 8) + kc + cA1, &As[s1 << 3]);
    gload16(Bhi + ((size_t)(n0 + rA0) << 8) + kc + cA0, &Bs[s0 << 3]);
    gload16(Bhi + ((size_t)(n0 + rA1) << 8) + kc + cA1, &Bs[s1 << 3]);
    __syncthreads();
    bf16x8 av[4], bv[4];
#pragma unroll
    for (int ai = 0; ai < 4; ++ai)
      av[ai] = *(const bf16x8*)&As[((wr << 6) + (ai << 4) + c) * 32 + (g << 3)];
#pragma unroll
    for (int bj = 0; bj < 4; ++bj)
      bv[bj] = *(const bf16x8*)&Bs[((wc << 6) + (bj << 4) + c) * 32 + (g << 3)];
#pragma unroll
    for (int ai = 0; ai < 4; ++ai)
#pragma unroll
      for (int bj = 0; bj < 4; ++bj)
        acc[ai][bj] = __builtin_amdgcn_mfma_f32_16x16x32_bf16(av[ai], bv[bj], acc[ai][bj], 0, 0, 0);
  }

  // epilogue: d = znf[m] + enormf[n] - 2*acc ; store d ; per-row top-2
  __syncthreads();
  float* sd1 = (float*)As;          // [128][2]
  int*   si1 = (int*)(sd1 + 256);
  float* sd2 = (float*)(si1 + 256);

  float zn_[4][4];
#pragma unroll
  for (int ai = 0; ai < 4; ++ai)
#pragma unroll
    for (int rg = 0; rg < 4; ++rg)
      zn_[ai][rg] = znf[m0 + (wr << 6) + (ai << 4) + (g << 2) + rg];
  float en_[4];
#pragma unroll
  for (int bj = 0; bj < 4; ++bj)
    en_[bj] = enormf[n0 + (wc << 6) + (bj << 4) + c];

#pragma unroll
  for (int ai = 0; ai < 4; ++ai) {
#pragma unroll
    for (int rg = 0; rg < 4; ++rg) {
      const int m = m0 + (wr << 6) + (ai << 4) + (g << 2) + rg;
      const float zr = zn_[ai][rg];
      float m1 = 3.0e38f, m2 = 3.0e38f; int i1 = 0;
#pragma unroll
      for (int bj = 0; bj < 4; ++bj) {
        const float S = zr + en_[bj];
        const float v = S - 2.0f * acc[ai][bj][rg];
        const int n = n0 + (wc << 6) + (bj << 4) + c;
        dmat[((size_t)m << 10) + n] = v;
        if (v < m1) { m2 = m1; m1 = v; i1 = n; }
        else if (v < m2) { m2 = v; }
      }
#pragma unroll
      for (int off = 8; off >= 1; off >>= 1) {
        const float o1 = __shfl_xor(m1, off, 16);
        const int   oi = __shfl_xor(i1, off, 16);
        const float o2 = __shfl_xor(m2, off, 16);
        const float ns = fminf(fminf(m2, o2), fmaxf(m1, o1));
        if (o1 < m1 || (o1 == m1 && oi < i1)) { m1 = o1; i1 = oi; }
        m2 = ns;
      }
      if (c == 0) {
        const int r = (wr << 6) + (ai << 4) + (g << 2) + rg;
        sd1[(r << 1) + wc] = m1; si1[(r << 1) + wc] = i1; sd2[(r << 1) + wc] = m2;
      }
    }
  }
  __syncthreads();
  if (t < 128) {
    const float a1 = sd1[t << 1], b1 = sd1[(t << 1) + 1];
    const int ai1 = si1[t << 1], bi1 = si1[(t << 1) + 1];
    const float a2 = sd2[t << 1], b2 = sd2[(t << 1) + 1];
    float d1, d2; int i1;
    if (b1 < a1 || (b1 == a1 && bi1 < ai1)) { d1 = b1; i1 = bi1; d2 = fminf(a1, b2); }
    else { d1 = a1; i1 = ai1; d2 = fminf(b1, a2); }
    float4 r; r.x = d1; r.y = __int_as_float(i1); r.z = d2; r.w = 0.0f;
    top2[(((size_t)(m0 + t)) << 3) + blockIdx.y] = r;
  }
}

// ---------- merge 8 per-block top-2s -> global top-2, flag near-ties ----------
__global__ __launch_bounds__(256) void vq_top2merge(const float4* __restrict__ top2,
    int* __restrict__ idxw, int* __restrict__ flag_cnt, int* __restrict__ flag_rows) {
  const int row = blockIdx.x * 256 + threadIdx.x;
  const float4* tp = top2 + ((size_t)row << 3);
  float4 e = tp[0];
  float d1 = e.x; int i1 = __float_as_int(e.y); float d2 = e.z;
  for (int k = 1; k < 8; ++k) {
    e = tp[k];
    const int ei = __float_as_int(e.y);
    if (e.x < d1 || (e.x == d1 && ei < i1)) { d2 = fminf(d1, e.z); d1 = e.x; i1 = ei; }
    else { d2 = fminf(d2, fminf(e.x, e.z)); }
  }
  idxw[row] = i1;
  if (d2 - d1 < THR_FLAG) {
    const int p = atomicAdd(flag_cnt, 1);
    flag_rows[p] = row;
  }
}

// ---------- candidate-based exact f32-chain refine (matches round-2 argmin) ----------
__global__ __launch_bounds__(256) void vq_refine(const float* __restrict__ z,
    const float* __restrict__ emb, const float* __restrict__ znf,
    const float* __restrict__ enormf, const float* __restrict__ dmat,
    const int* __restrict__ flag_cnt, const int* __restrict__ flag_rows,
    int* __restrict__ idxw) {
  __shared__ float zrow[256];
  __shared__ float dmin_s[4];
  __shared__ int cand[256];
  __shared__ int ncand_s;
  __shared__ float rv[256];
  __shared__ int ri[256];
  const int t = threadIdx.x;
  const int n = *flag_cnt;
  for (int f = blockIdx.x; f < n; f += gridDim.x) {
    const int m = flag_rows[f];
    __syncthreads();                                  // protect reuse across iterations
    if (t == 0) ncand_s = 0;
    zrow[t] = z[(((size_t)(m >> 12)) << 20) + (size_t)(m & 4095) + ((size_t)t << 12)];
    const float* dr = dmat + ((size_t)m << 10);
    const float2 a = *(const float2*)&dr[t << 2];
    const float2 b = *(const float2*)&dr[(t << 2) + 2];
    float dmin = fminf(fminf(a.x, a.y), fminf(b.x, b.y));
    for (int off = 32; off >= 1; off >>= 1) dmin = fminf(dmin, __shfl_xor(dmin, off));
    if ((t & 63) == 0) dmin_s[t >> 6] = dmin;
    __syncthreads();
    dmin = fminf(fminf(dmin_s[0], dmin_s[1]), fminf(dmin_s[2], dmin_s[3]));
    const float lim = dmin + THR_FLAG;
    const float dv[4] = {a.x, a.y, b.x, b.y};
#pragma unroll
    for (int q = 0; q < 4; ++q)
      if (dv[q] <= lim) {
        const int p = atomicAdd(&ncand_s, 1);
        if (p < 256) cand[p] = (t << 2) + q;
      }
    __syncthreads();
    const int nc = min(ncand_s, 256);
    float best = 3.0e38f; int bi = 1 << 30;
    if (t < nc) {
      const int j = cand[t];
      const float* er = emb + ((size_t)j << 8);
      float s = 0.0f;
      for (int k = 0; k < 256; ++k) s = fmaf(zrow[k], er[k], s);
      const float S = znf[m] + enormf[j];
      best = S - 2.0f * s;
      bi = j;
    }
    rv[t] = best; ri[t] = bi;
    __syncthreads();
    for (int off = 128; off > 0; off >>= 1) {
      if (t < off) {
        const float ov = rv[t + off]; const int oi = ri[t + off];
        if (ov < rv[t] || (ov == rv[t] && oi < ri[t])) { rv[t] = ov; ri[t] = oi; }
      }
      __syncthreads();
    }
    if (t == 0) idxw[m] = ri[0];
  }
}

// ================= round-2 fallback dist kernel (proven) =================
__global__ __launch_bounds__(256) void vq_enorm_old(const float* __restrict__ emb,
                                                    float* __restrict__ enormf) {
  const int j = blockIdx.x * 256 + threadIdx.x;
  const float* e = emb + ((size_t)j << 8);
  double s = 0.0;
  for (int k = 0; k < 256; ++k) { const double v = (double)e[k]; s += v * v; }
  enormf[j] = (float)s;
}

__global__ __launch_bounds__(256) void vq_dist_old(const float* __restrict__ z,
    const float* __restrict__ emb, const float* __restrict__ enormf,
    float* __restrict__ dmat, int* __restrict__ idxw) {
  __shared__ float As[256][68];
  __shared__ float Bs[32][68];
  __shared__ float znf[64];
  const int t = threadIdx.x;
  const int lane = t & 63;
  const int quad = t >> 6;
  const int blk = blockIdx.x;
  const int base = blk << 6;
  const float* zb = z + (((size_t)(blk >> 6)) << 20) + (((size_t)(blk & 63)) << 6);
  {
    const int kr = t >> 4;
    const int xc = (t & 15) << 2;
    for (int k0 = 0; k0 < 256; k0 += 16) {
      const int k = k0 + kr;
      const float4 v = *(const float4*)&zb[((size_t)k << 12) + xc];
      *(float4*)&As[k][xc] = v;
    }
  }
  __syncthreads();
  {
    double* znp = (double*)&Bs[0][0];
    double s = 0.0;
    const int kb = quad << 6;
    for (int k = 0; k < 64; ++k) { const double v = (double)As[kb + k][lane]; s += v * v; }
    znp[(lane << 2) + quad] = s;
    __syncthreads();
    if (t < 64) {
      const double* zp = znp + (t << 2);
      znf[t] = (float)(zp[0] + zp[1] + zp[2] + zp[3]);
    }
  }
  const int tj = t & 15;
  const int tm = t >> 4;
  float m1[4]; int i1[4];
#pragma unroll
  for (int mm = 0; mm < 4; ++mm) { m1[mm] = 3.0e38f; i1[mm] = 0; }
  for (int jt = 0; jt < 16; ++jt) {
    const int j0 = jt << 6;
    float acc[4][4];
#pragma unroll
    for (int a = 0; a < 4; ++a)
#pragma unroll
      for (int q = 0; q < 4; ++q) acc[a][q] = 0.0f;
    for (int kc = 0; kc < 256; kc += 32) {
      __syncthreads();
#pragma unroll
      for (int i = 0; i < 8; ++i) {
        const int jl = (i << 3) + (t >> 5);
        const int kl = t & 31;
        Bs[kl][jl] = emb[(((size_t)(j0 + jl)) << 8) + kc + kl];
      }
      __syncthreads();
#pragma unroll
      for (int k2 = 0; k2 < 32; ++k2) {
        const float4 av = *(const float4*)&As[kc + k2][tm << 2];
        const float4 bv = *(const float4*)&Bs[k2][tj << 2];
        acc[0][0] = fmaf(av.x, bv.x, acc[0][0]);
        acc[0][1] = fmaf(av.x, bv.y, acc[0][1]);
        acc[0][2] = fmaf(av.x, bv.z, acc[0][2]);
        acc[0][3] = fmaf(av.x, bv.w, acc[0][3]);
        acc[1][0] = fmaf(av.y, bv.x, acc[1][0]);
        acc[1][1] = fmaf(av.y, bv.y, acc[1][1]);
        acc[1][2] = fmaf(av.y, bv.z, acc[1][2]);
        acc[1][3] = fmaf(av.y, bv.w, acc[1][3]);
        acc[2][0] = fmaf(av.z, bv.x, acc[2][0]);
        acc[2][1] = fmaf(av.z, bv.y, acc[2][1]);
        acc[2][2] = fmaf(av.z, bv.z, acc[2][2]);
        acc[2][3] = fmaf(av.z, bv.w, acc[2][3]);
        acc[3][0] = fmaf(av.w, bv.x, acc[3][0]);
        acc[3][1] = fmaf(av.w, bv.y, acc[3][1]);
        acc[3][2] = fmaf(av.w, bv.z, acc[3][2]);
        acc[3][3] = fmaf(av.w, bv.w, acc[3][3]);
      }
    }
    float ej[4];
#pragma unroll
    for (int q = 0; q < 4; ++q) ej[q] = enormf[j0 + (tj << 2) + q];
#pragma unroll
    for (int mm = 0; mm < 4; ++mm) {
      const int row = (tm << 2) + mm;
      const float zr = znf[row];
      float qv[4];
#pragma unroll
      for (int q = 0; q < 4; ++q) {
        const float S = zr + ej[q];
        qv[q] = S - 2.0f * acc[mm][q];
      }
      float2* dst = (float2*)&dmat[((size_t)(base + row) << 10) + j0 + (tj << 2)];
      dst[0] = make_float2(qv[0], qv[1]);
      dst[1] = make_float2(qv[2], qv[3]);
#pragma unroll
      for (int q = 0; q < 4; ++q) {
        const float v = qv[q];
        if (v < m1[mm]) { m1[mm] = v; i1[mm] = j0 + (tj << 2) + q; }
      }
    }
  }
#pragma unroll
  for (int mm = 0; mm < 4; ++mm) {
    float a1 = m1[mm]; int ai = i1[mm];
    for (int off = 8; off >= 1; off >>= 1) {
      const float o1 = __shfl_xor(a1, off, 16);
      const int   oi = __shfl_xor(ai, off, 16);
      if (o1 < a1 || (o1 == a1 && oi < ai)) { a1 = o1; ai = oi; }
    }
    if (tj == 0) idxw[base + (tm << 2) + mm] = ai;
  }
}

// ================= shared tail kernels =================
__global__ __launch_bounds__(256) void vq_zq(const float* __restrict__ z,
    const float* __restrict__ emb, const int* __restrict__ idxw,
    float* __restrict__ zq, double* __restrict__ loss_part) {
  __shared__ float E[64][258];
  __shared__ int il[64];
  __shared__ double red[256];
  const int t = threadIdx.x;
  const int blk = blockIdx.x;
  const int base = blk << 6;
  if (t < 64) il[t] = idxw[base + t];
  __syncthreads();
  for (int i = 0; i < 64; ++i) E[i][t] = emb[((size_t)il[i] << 8) + t];
  __syncthreads();
  const int w = t & 63, cg = t >> 6;
  const size_t zbase = (((size_t)(blk >> 6)) << 20) + (((size_t)(blk & 63)) << 6) + (size_t)w;
  double ls = 0.0;
  for (int ci = 0; ci < 64; ++ci) {
    const int c = (ci << 2) + cg;
    const float e = E[w][c];
    const size_t o = zbase + ((size_t)c << 12);
    const float zv = z[o];
    zq[o] = e;
    const double dd = (double)e - (double)zv;
    ls += dd * dd;
  }
  red[t] = ls;
  __syncthreads();
  for (int off = 128; off > 0; off >>= 1) {
    if (t < off) red[t] += red[t + off];
    __syncthreads();
  }
  if (t == 0) loss_part[blk] = red[0];
}

__global__ __launch_bounds__(256) void vq_scatter(const int* __restrict__ idxw,
    float* __restrict__ out, int* __restrict__ hist) {
  const int m = blockIdx.x * 256 + threadIdx.x;
  const int idx = idxw[m];
  out[O_OH + ((size_t)m << 10) + (size_t)idx] = 1.0f;
  out[O_IDX + (size_t)m] = (float)idx;
  atomicAdd(&hist[idx], 1);
}

__global__ __launch_bounds__(256) void vq_final(const double* __restrict__ loss_part,
    const int* __restrict__ hist, float* __restrict__ out) {
  __shared__ double red[256];
  const int t = threadIdx.x;
  double s = 0.0;
  for (int i = t; i < 1024; i += 256) s += loss_part[i];
  red[t] = s;
  __syncthreads();
  for (int off = 128; off > 0; off >>= 1) {
    if (t < off) red[t] += red[t + off];
    __syncthreads();
  }
  if (t == 0) out[O_LOSS] = (float)(1.25 * red[0] / 16777216.0);
  __syncthreads();
  double h = 0.0;
  for (int i = t; i < 1024; i += 256) {
    const double p = (double)hist[i] / 65536.0;
    h += p * log(p + 1e-10);
  }
  red[t] = h;
  __syncthreads();
  for (int off = 128; off > 0; off >>= 1) {
    if (t < off) red[t] += red[t + off];
    __syncthreads();
  }
  if (t == 0) out[O_PERP] = (float)exp(-red[0]);
}

extern "C" void kernel_launch(void* const* d_in, const int* in_sizes, int n_in,
                              void* d_out, int out_size, void* d_ws, size_t ws_size,
                              hipStream_t stream) {
  const float* z   = (const float*)d_in[0];
  const float* emb = (const float*)d_in[1];
  float* out = (float*)d_out;
  char* ws = (char*)d_ws;

  if (ws_size >= WS_NEEDED) {
    float*  enormf    = (float*)(ws + WS_ENORM);
    float*  znf       = (float*)(ws + WS_ZNF);
    int*    idxw      = (int*)(ws + WS_IDX);
    int*    hist      = (int*)(ws + WS_HIST);
    int*    flag_cnt  = (int*)(ws + WS_FCNT);
    int*    flag_rows = (int*)(ws + WS_FROWS);
    double* loss_part = (double*)(ws + WS_LOSS);
    float4* top2      = (float4*)(ws + WS_TOP2);
    ushort* Ahi       = (ushort*)(ws + WS_AHI);
    ushort* Bhi       = (ushort*)(ws + WS_BHI);

    vq_prep_e<<<4, 256, 0, stream>>>(emb, enormf, Bhi);
    vq_prep_z<<<1024, 256, 0, stream>>>(z, Ahi, znf);
    hipMemsetAsync(ws + WS_HIST, 0, 4112, stream);            // hist + flag_cnt
    hipMemsetAsync((char*)d_out + O_OH * sizeof(float), 0,
                   (size_t)67108864 * sizeof(float), stream); // one_hot zeros
    dim3 g(512, 8);
    vq_gemm<<<g, 256, 0, stream>>>(Ahi, Bhi, znf, enormf, out + O_D, top2);
    vq_top2merge<<<256, 256, 0, stream>>>(top2, idxw, flag_cnt, flag_rows);
    vq_refine<<<4096, 256, 0, stream>>>(z, emb, znf, enormf, out + O_D,
                                        flag_cnt, flag_rows, idxw);
    vq_zq<<<1024, 256, 0, stream>>>(z, emb, idxw, out, loss_part);
    vq_scatter<<<256, 256, 0, stream>>>(idxw, out, hist);
    vq_final<<<1, 256, 0, stream>>>(loss_part, hist, out);
  } else {
    // proven round-2 path
    float*  enormf    = (float*)(ws + 0);
    int*    idxw      = (int*)(ws + 4096);
    int*    hist      = (int*)(ws + 266240);
    double* loss_part = (double*)(ws + 270336);

    vq_enorm_old<<<4, 256, 0, stream>>>(emb, enormf);
    hipMemsetAsync(ws + 266240, 0, 4096, stream);
    hipMemsetAsync((char*)d_out + O_OH * sizeof(float), 0,
                   (size_t)67108864 * sizeof(float), stream);
    vq_dist_old<<<1024, 256, 0, stream>>>(z, emb, enormf, out + O_D, idxw);
    vq_zq<<<1024, 256, 0, stream>>>(z, emb, idxw, out, loss_part);
    vq_scatter<<<256, 256, 0, stream>>>(idxw, out, hist);
    vq_final<<<1, 256, 0, stream>>>(loss_part, hist, out);
  }
}

// Round 5
// 387.337 us; speedup vs baseline: 2.7303x; 1.0720x over previous
//
#include <hip/hip_runtime.h>
#include <math.h>

// VQ-VAE forward on MI355X (gfx950).
// z: (16,256,64,64) f32 ; emb: (1024,256) f32
// Outputs flat f32: z_q(16.7M) | loss | perp | one_hot(67.1M) | idx(65536) | d(67.1M)
//
// Round-5: 2-phase BK=128 bf16 MFMA GEMM (4 barriers total vs 16), one_hot fill fused
// into scatter (full-row writes), loss taken from d1 (exact identity d=||z-e||^2),
// zq slimmed to pure gather-broadcast. Argmin semantics unchanged from validated
// rounds 2-4: bf16 approx + top-2 flag (THR=4e-4 ~ 9.5 sigma) + exact-f32-chain refine.

typedef unsigned short ushort;
typedef unsigned int uint;
typedef __attribute__((ext_vector_type(8))) short  bf16x8;
typedef __attribute__((ext_vector_type(8))) ushort ushort8v;
typedef __attribute__((ext_vector_type(4))) float  f32x4;

static const size_t O_LOSS = 16777216;
static const size_t O_PERP = 16777217;
static const size_t O_OH   = 16777218;   // byte off 8 mod 16 -> float2 access only
static const size_t O_IDX  = 83886082;
static const size_t O_D    = 83951618;   // byte off 8 mod 16 -> float2 access only

// ---- ws layout (bytes) ----
static const size_t WS_ENORM = 0;          // f32[1024]
static const size_t WS_ZNF   = 4096;       // f32[65536]
static const size_t WS_IDX   = 266240;     // i32[65536]
static const size_t WS_HIST  = 528384;     // i32[1024]
static const size_t WS_FCNT  = 532480;     // i32 (+pad)
static const size_t WS_FROWS = 532496;     // i32[65536]
static const size_t WS_LOSS  = 794640;     // f64[256]
static const size_t WS_TOP2  = 802832;     // float4[65536*8]  (8 MB)
static const size_t WS_AHI   = 9191440;    // bf16[65536*256]  (32 MB)
static const size_t WS_BHI   = 42745872;   // bf16[1024*256]   (512 KB)

#define THR_FLAG 4e-4f

__device__ __forceinline__ ushort f2bf(float f) {
  uint u = __float_as_uint(f);
  return (ushort)((u + 0x7FFFu + ((u >> 16) & 1u)) >> 16);   // RNE
}
__device__ __forceinline__ void gload16(const void* g, void* l) {
  __builtin_amdgcn_global_load_lds(
      (const __attribute__((address_space(1))) void*)g,
      (__attribute__((address_space(3))) void*)l, 16, 0, 0);
}

// ---------- prep: emb -> enormf (f64 seq, round once) + B = bf16(emb); init hist/fcnt ----------
__global__ __launch_bounds__(256) void vq_prep_e(const float* __restrict__ emb,
    float* __restrict__ enormf, ushort* __restrict__ Bhi,
    int* __restrict__ hist, int* __restrict__ flag_cnt) {
  const int j = blockIdx.x * 256 + threadIdx.x;
  hist[j] = 0;
  if (j == 0) *flag_cnt = 0;
  const float* e = emb + ((size_t)j << 8);
  ushort* br = Bhi + ((size_t)j << 8);
  double s = 0.0;
  for (int k0 = 0; k0 < 256; k0 += 8) {
    const float4 a = *(const float4*)&e[k0];
    const float4 b = *(const float4*)&e[k0 + 4];
    ushort8v v;
    v[0] = f2bf(a.x); v[1] = f2bf(a.y); v[2] = f2bf(a.z); v[3] = f2bf(a.w);
    v[4] = f2bf(b.x); v[5] = f2bf(b.y); v[6] = f2bf(b.z); v[7] = f2bf(b.w);
    *(ushort8v*)&br[k0] = v;
    s += (double)a.x * (double)a.x;  s += (double)a.y * (double)a.y;
    s += (double)a.z * (double)a.z;  s += (double)a.w * (double)a.w;
    s += (double)b.x * (double)b.x;  s += (double)b.y * (double)b.y;
    s += (double)b.z * (double)b.z;  s += (double)b.w * (double)b.w;
  }
  enormf[j] = (float)s;
}

// ---------- prep: z -> A = bf16(z) row-major [m][256], znf (f64, round once) ----------
__global__ __launch_bounds__(256) void vq_prep_z(const float* __restrict__ z,
    ushort* __restrict__ Ahi, float* __restrict__ znf) {
  __shared__ float As[256][68];
  __shared__ double znp[64][4];
  const int t = threadIdx.x;
  const int lane = t & 63, quad = t >> 6;
  const int blk = blockIdx.x;
  const float* zb = z + (((size_t)(blk >> 6)) << 20) + (((size_t)(blk & 63)) << 6);
  {
    const int kr = t >> 4, xc = (t & 15) << 2;
    for (int k0 = 0; k0 < 256; k0 += 16) {
      const int k = k0 + kr;
      *(float4*)&As[k][xc] = *(const float4*)&zb[((size_t)k << 12) + xc];
    }
  }
  __syncthreads();
  {
    double s = 0.0;
    const int kb = quad << 6;
    for (int k = 0; k < 64; ++k) { const double v = (double)As[kb + k][lane]; s += v * v; }
    znp[lane][quad] = s;
  }
  __syncthreads();
  const int m0 = ((blk >> 6) << 12) + ((blk & 63) << 6);
  if (t < 64) znf[m0 + t] = (float)(znp[t][0] + znp[t][1] + znp[t][2] + znp[t][3]);
  const int row = t >> 2;
  ushort* dst = Ahi + ((size_t)(m0 + row) << 8);
  for (int s = 0; s < 8; ++s) {
    const int k0 = ((t & 3) + (s << 2)) << 3;
    ushort8v v;
#pragma unroll
    for (int i = 0; i < 8; ++i) v[i] = f2bf(As[k0 + i][row]);
    *(ushort8v*)&dst[k0] = v;
  }
}

// ---------- main: 128x128 bf16 MFMA GEMM, 2 phases of BK=128 (4 barriers total) ----------
__global__ __launch_bounds__(256) void vq_gemm(const ushort* __restrict__ Ahi,
    const ushort* __restrict__ Bhi, const float* __restrict__ znf,
    const float* __restrict__ enormf, float* __restrict__ dmat,
    float4* __restrict__ top2) {
  __shared__ ushort As[16384];   // 4 chunks x [128 rows][32 k] = 32 KB
  __shared__ ushort Bs[16384];

  const int t = threadIdx.x;
  const int lane = t & 63;
  const int w = t >> 6;
  const int wr = w >> 1, wc = w & 1;
  const int g = lane >> 4, cl = lane & 15;
  const int m0 = blockIdx.x << 7;
  const int n0 = blockIdx.y << 7;

  f32x4 acc[4][4];
#pragma unroll
  for (int a = 0; a < 4; ++a)
#pragma unroll
    for (int b = 0; b < 4; ++b) acc[a][b] = (f32x4)(0.0f);

  // staging slots: s in [0,512): row=s>>2, 16B group q=s&3 (within 64B = 32-ushort row)
  const int s0 = t, s1 = 256 + t;
  const int rA0 = s0 >> 2, cA0 = (s0 & 3) << 3;
  const int rA1 = s1 >> 2, cA1 = (s1 & 3) << 3;

#pragma unroll
  for (int p = 0; p < 2; ++p) {
    const int kb = p << 7;
    __syncthreads();                       // prior-phase LDS reads done
#pragma unroll
    for (int c = 0; c < 4; ++c) {
      const int koff = kb + (c << 5);
      gload16(Ahi + ((size_t)(m0 + rA0) << 8) + koff + cA0, &As[(c << 12) + (s0 << 3)]);
      gload16(Ahi + ((size_t)(m0 + rA1) << 8) + koff + cA1, &As[(c << 12) + (s1 << 3)]);
      gload16(Bhi + ((size_t)(n0 + rA0) << 8) + koff + cA0, &Bs[(c << 12) + (s0 << 3)]);
      gload16(Bhi + ((size_t)(n0 + rA1) << 8) + koff + cA1, &Bs[(c << 12) + (s1 << 3)]);
    }
    __syncthreads();                       // implicit vmcnt(0) drain
#pragma unroll
    for (int c2 = 0; c2 < 4; ++c2) {
      bf16x8 av[4], bv[4];
#pragma unroll
      for (int ai = 0; ai < 4; ++ai)
        av[ai] = *(const bf16x8*)&As[(c2 << 12) + ((wr << 6) + (ai << 4) + cl) * 32 + (g << 3)];
#pragma unroll
      for (int bj = 0; bj < 4; ++bj)
        bv[bj] = *(const bf16x8*)&Bs[(c2 << 12) + ((wc << 6) + (bj << 4) + cl) * 32 + (g << 3)];
#pragma unroll
      for (int ai = 0; ai < 4; ++ai)
#pragma unroll
        for (int bj = 0; bj < 4; ++bj)
          acc[ai][bj] = __builtin_amdgcn_mfma_f32_16x16x32_bf16(av[ai], bv[bj], acc[ai][bj], 0, 0, 0);
    }
  }

  // epilogue: d = znf[m] + enormf[n] - 2*acc ; store d ; per-row top-2
  __syncthreads();
  float* sd1 = (float*)As;          // [128][2]
  int*   si1 = (int*)(sd1 + 256);
  float* sd2 = (float*)(si1 + 256);

  float zn_[4][4];
#pragma unroll
  for (int ai = 0; ai < 4; ++ai)
#pragma unroll
    for (int rg = 0; rg < 4; ++rg)
      zn_[ai][rg] = znf[m0 + (wr << 6) + (ai << 4) + (g << 2) + rg];
  float en_[4];
#pragma unroll
  for (int bj = 0; bj < 4; ++bj)
    en_[bj] = enormf[n0 + (wc << 6) + (bj << 4) + cl];

#pragma unroll
  for (int ai = 0; ai < 4; ++ai) {
#pragma unroll
    for (int rg = 0; rg < 4; ++rg) {
      const int m = m0 + (wr << 6) + (ai << 4) + (g << 2) + rg;
      const float zr = zn_[ai][rg];
      float m1 = 3.0e38f, m2 = 3.0e38f; int i1 = 0;
#pragma unroll
      for (int bj = 0; bj < 4; ++bj) {
        const float S = zr + en_[bj];
        const float v = S - 2.0f * acc[ai][bj][rg];
        const int n = n0 + (wc << 6) + (bj << 4) + cl;
        dmat[((size_t)m << 10) + n] = v;
        if (v < m1) { m2 = m1; m1 = v; i1 = n; }
        else if (v < m2) { m2 = v; }
      }
#pragma unroll
      for (int off = 8; off >= 1; off >>= 1) {
        const float o1 = __shfl_xor(m1, off, 16);
        const int   oi = __shfl_xor(i1, off, 16);
        const float o2 = __shfl_xor(m2, off, 16);
        const float ns = fminf(fminf(m2, o2), fmaxf(m1, o1));
        if (o1 < m1 || (o1 == m1 && oi < i1)) { m1 = o1; i1 = oi; }
        m2 = ns;
      }
      if (cl == 0) {
        const int r = (wr << 6) + (ai << 4) + (g << 2) + rg;
        sd1[(r << 1) + wc] = m1; si1[(r << 1) + wc] = i1; sd2[(r << 1) + wc] = m2;
      }
    }
  }
  __syncthreads();
  if (t < 128) {
    const float a1 = sd1[t << 1], b1 = sd1[(t << 1) + 1];
    const int ai1 = si1[t << 1], bi1 = si1[(t << 1) + 1];
    const float a2 = sd2[t << 1], b2 = sd2[(t << 1) + 1];
    float d1, d2; int i1;
    if (b1 < a1 || (b1 == a1 && bi1 < ai1)) { d1 = b1; i1 = bi1; d2 = fminf(a1, b2); }
    else { d1 = a1; i1 = ai1; d2 = fminf(b1, a2); }
    float4 r; r.x = d1; r.y = __int_as_float(i1); r.z = d2; r.w = 0.0f;
    top2[(((size_t)(m0 + t)) << 3) + blockIdx.y] = r;
  }
}

// ---------- merge 8 per-block top-2s -> global top-2, flag near-ties, loss partial ----------
__global__ __launch_bounds__(256) void vq_top2merge(const float4* __restrict__ top2,
    int* __restrict__ idxw, int* __restrict__ flag_cnt, int* __restrict__ flag_rows,
    double* __restrict__ loss_part) {
  __shared__ double red[256];
  const int t = threadIdx.x;
  const int row = blockIdx.x * 256 + t;
  const float4* tp = top2 + ((size_t)row << 3);
  float4 e = tp[0];
  float d1 = e.x; int i1 = __float_as_int(e.y); float d2 = e.z;
  for (int k = 1; k < 8; ++k) {
    e = tp[k];
    const int ei = __float_as_int(e.y);
    if (e.x < d1 || (e.x == d1 && ei < i1)) { d2 = fminf(d1, e.z); d1 = e.x; i1 = ei; }
    else { d2 = fminf(d2, fminf(e.x, e.z)); }
  }
  idxw[row] = i1;
  if (d2 - d1 < THR_FLAG) {
    const int p = atomicAdd(flag_cnt, 1);
    flag_rows[p] = row;
  }
  // loss partial: d1 = ||z_m - e_idx||^2 (+ ~3e-5 bf16 error; loss threshold ~20)
  red[t] = (double)d1;
  __syncthreads();
  for (int off = 128; off > 0; off >>= 1) {
    if (t < off) red[t] += red[t + off];
    __syncthreads();
  }
  if (t == 0) loss_part[blockIdx.x] = red[0];
}

// ---------- candidate-based exact f32-chain refine (matches round-2 argmin) ----------
__global__ __launch_bounds__(256) void vq_refine(const float* __restrict__ z,
    const float* __restrict__ emb, const float* __restrict__ znf,
    const float* __restrict__ enormf, const float* __restrict__ dmat,
    const int* __restrict__ flag_cnt, const int* __restrict__ flag_rows,
    int* __restrict__ idxw) {
  __shared__ float zrow[256];
  __shared__ float dmin_s[4];
  __shared__ int cand[256];
  __shared__ int ncand_s;
  __shared__ float rv[256];
  __shared__ int ri[256];
  const int t = threadIdx.x;
  const int n = *flag_cnt;
  for (int f = blockIdx.x; f < n; f += gridDim.x) {
    const int m = flag_rows[f];
    __syncthreads();
    if (t == 0) ncand_s = 0;
    zrow[t] = z[(((size_t)(m >> 12)) << 20) + (size_t)(m & 4095) + ((size_t)t << 12)];
    const float* dr = dmat + ((size_t)m << 10);
    const float2 a = *(const float2*)&dr[t << 2];
    const float2 b = *(const float2*)&dr[(t << 2) + 2];
    float dmin = fminf(fminf(a.x, a.y), fminf(b.x, b.y));
    for (int off = 32; off >= 1; off >>= 1) dmin = fminf(dmin, __shfl_xor(dmin, off));
    if ((t & 63) == 0) dmin_s[t >> 6] = dmin;
    __syncthreads();
    dmin = fminf(fminf(dmin_s[0], dmin_s[1]), fminf(dmin_s[2], dmin_s[3]));
    const float lim = dmin + THR_FLAG;
    const float dv[4] = {a.x, a.y, b.x, b.y};
#pragma unroll
    for (int q = 0; q < 4; ++q)
      if (dv[q] <= lim) {
        const int p = atomicAdd(&ncand_s, 1);
        if (p < 256) cand[p] = (t << 2) + q;
      }
    __syncthreads();
    const int nc = min(ncand_s, 256);
    float best = 3.0e38f; int bi = 1 << 30;
    if (t < nc) {
      const int j = cand[t];
      const float* er = emb + ((size_t)j << 8);
      float s = 0.0f;
      for (int k = 0; k < 256; ++k) s = fmaf(zrow[k], er[k], s);
      const float S = znf[m] + enormf[j];
      best = S - 2.0f * s;
      bi = j;
    }
    rv[t] = best; ri[t] = bi;
    __syncthreads();
    for (int off = 128; off > 0; off >>= 1) {
      if (t < off) {
        const float ov = rv[t + off]; const int oi = ri[t + off];
        if (ov < rv[t] || (ov == rv[t] && oi < ri[t])) { rv[t] = ov; ri[t] = oi; }
      }
      __syncthreads();
    }
    if (t == 0) idxw[m] = ri[0];
  }
}

// ---------- z_q gather-broadcast (no z read; loss comes from d) ----------
__global__ __launch_bounds__(256) void vq_zq(const float* __restrict__ emb,
    const int* __restrict__ idxw, float* __restrict__ zq) {
  __shared__ float E[64][258];
  __shared__ int il[64];
  const int t = threadIdx.x;
  const int blk = blockIdx.x;
  const int base = blk << 6;
  if (t < 64) il[t] = idxw[base + t];
  __syncthreads();
  for (int i = 0; i < 64; ++i) E[i][t] = emb[((size_t)il[i] << 8) + t];
  __syncthreads();
  const int w = t & 63, cg = t >> 6;
  const size_t zbase = (((size_t)(blk >> 6)) << 20) + (((size_t)(blk & 63)) << 6) + (size_t)w;
  for (int ci = 0; ci < 64; ++ci) {
    const int c = (ci << 2) + cg;
    zq[zbase + ((size_t)c << 12)] = E[w][c];
  }
}

// ---------- scatter: full one_hot rows (replaces 268MB memset) + idx + hist ----------
__global__ __launch_bounds__(256) void vq_scatter(const int* __restrict__ idxw,
    float* __restrict__ out, int* __restrict__ hist) {
  const int t = threadIdx.x;
  const int w = t >> 6, l = t & 63;
  const int rbase = (blockIdx.x << 6) + (w << 4);
  for (int rr = 0; rr < 16; ++rr) {
    const int m = rbase + rr;
    const int idx = idxw[m];
    float2* row = (float2*)(out + O_OH + ((size_t)m << 10));
    const int half = idx >> 1;
#pragma unroll
    for (int i = 0; i < 8; ++i) {
      const int slot = (i << 6) + l;
      float2 v; v.x = 0.0f; v.y = 0.0f;
      if (slot == half) { if (idx & 1) v.y = 1.0f; else v.x = 1.0f; }
      row[slot] = v;
    }
    if (l == 0) {
      out[O_IDX + m] = (float)idx;
      atomicAdd(&hist[idx], 1);
    }
  }
}

__global__ __launch_bounds__(256) void vq_final(const double* __restrict__ loss_part,
    const int* __restrict__ hist, float* __restrict__ out) {
  __shared__ double red[256];
  const int t = threadIdx.x;
  red[t] = loss_part[t];
  __syncthreads();
  for (int off = 128; off > 0; off >>= 1) {
    if (t < off) red[t] += red[t + off];
    __syncthreads();
  }
  if (t == 0) out[O_LOSS] = (float)(1.25 * red[0] / 16777216.0);
  __syncthreads();
  double h = 0.0;
  for (int i = t; i < 1024; i += 256) {
    const double p = (double)hist[i] / 65536.0;
    h += p * log(p + 1e-10);
  }
  red[t] = h;
  __syncthreads();
  for (int off = 128; off > 0; off >>= 1) {
    if (t < off) red[t] += red[t + off];
    __syncthreads();
  }
  if (t == 0) out[O_PERP] = (float)exp(-red[0]);
}

extern "C" void kernel_launch(void* const* d_in, const int* in_sizes, int n_in,
                              void* d_out, int out_size, void* d_ws, size_t ws_size,
                              hipStream_t stream) {
  const float* z   = (const float*)d_in[0];
  const float* emb = (const float*)d_in[1];
  float* out = (float*)d_out;
  char* ws = (char*)d_ws;

  float*  enormf    = (float*)(ws + WS_ENORM);
  float*  znf       = (float*)(ws + WS_ZNF);
  int*    idxw      = (int*)(ws + WS_IDX);
  int*    hist      = (int*)(ws + WS_HIST);
  int*    flag_cnt  = (int*)(ws + WS_FCNT);
  int*    flag_rows = (int*)(ws + WS_FROWS);
  double* loss_part = (double*)(ws + WS_LOSS);
  float4* top2      = (float4*)(ws + WS_TOP2);
  ushort* Ahi       = (ushort*)(ws + WS_AHI);
  ushort* Bhi       = (ushort*)(ws + WS_BHI);

  vq_prep_e<<<4, 256, 0, stream>>>(emb, enormf, Bhi, hist, flag_cnt);
  vq_prep_z<<<1024, 256, 0, stream>>>(z, Ahi, znf);
  dim3 g(512, 8);
  vq_gemm<<<g, 256, 0, stream>>>(Ahi, Bhi, znf, enormf, out + O_D, top2);
  vq_top2merge<<<256, 256, 0, stream>>>(top2, idxw, flag_cnt, flag_rows, loss_part);
  vq_refine<<<4096, 256, 0, stream>>>(z, emb, znf, enormf, out + O_D,
                                      flag_cnt, flag_rows, idxw);
  vq_zq<<<1024, 256, 0, stream>>>(emb, idxw, out);
  vq_scatter<<<1024, 256, 0, stream>>>(idxw, out, hist);
  vq_final<<<1, 256, 0, stream>>>(loss_part, hist, out);
}

// Round 6
// 326.568 us; speedup vs baseline: 3.2384x; 1.1861x over previous
//
#include <hip/hip_runtime.h>
#include <math.h>

// VQ-VAE forward on MI355X (gfx950).
// z: (16,256,64,64) f32 ; emb: (1024,256) f32
// Outputs flat f32: z_q(16.7M) | loss | perp | one_hot(67.1M) | idx(65536) | d(67.1M)
//
// Round-6 "mega": one block = 128 rows x all 1024 codes. A staged once (64KB LDS,
// k-XOR-swizzled, pre-swizzled in global so global_load_lds stays linear); B 8KB
// chunks double-buffered with issue-before-compute prefetch; per-row top-2 carried
// in registers across the n-loop; block writes d, idx, one_hot, hist, loss directly.
// Argmin semantics unchanged (validated r2-r5): bf16 approx + THR=4e-4 near-tie flag
// + exact-f32-chain candidate refine (refine also patches idx/one_hot/hist).

typedef unsigned short ushort;
typedef unsigned int uint;
typedef __attribute__((ext_vector_type(8))) short  bf16x8;
typedef __attribute__((ext_vector_type(8))) ushort ushort8v;
typedef __attribute__((ext_vector_type(4))) float  f32x4;

static const size_t O_LOSS = 16777216;
static const size_t O_PERP = 16777217;
static const size_t O_OH   = 16777218;   // *4 bytes => 8 mod 16 -> float2 max
static const size_t O_IDX  = 83886082;
static const size_t O_D    = 83951618;   // float2 max

// ---- ws layout (bytes) ----
static const size_t WS_ENORM = 0;          // f32[1024]
static const size_t WS_ZNF   = 4096;       // f32[65536]
static const size_t WS_IDX   = 266240;     // i32[65536]
static const size_t WS_HIST  = 528384;     // i32[1024]
static const size_t WS_FCNT  = 532480;     // i32 (+pad)
static const size_t WS_FROWS = 532496;     // i32[65536]
static const size_t WS_LOSS  = 794640;     // f64[512]
static const size_t WS_AHI   = 9191440;    // bf16[65536*256] (32 MB), k-swizzled
static const size_t WS_BHI   = 42745872;   // bf16[1024*256]  (512 KB), linear

#define THR_FLAG 4e-4f

__device__ __forceinline__ ushort f2bf(float f) {
  uint u = __float_as_uint(f);
  return (ushort)((u + 0x7FFFu + ((u >> 16) & 1u)) >> 16);   // RNE
}
__device__ __forceinline__ void gload16(const void* g, void* l) {
  __builtin_amdgcn_global_load_lds(
      (const __attribute__((address_space(1))) void*)g,
      (__attribute__((address_space(3))) void*)l, 16, 0, 0);
}

// ---------- prep: emb -> enormf (f64 seq, round once) + B = bf16(emb); init hist/fcnt ----------
__global__ __launch_bounds__(256) void vq_prep_e(const float* __restrict__ emb,
    float* __restrict__ enormf, ushort* __restrict__ Bhi,
    int* __restrict__ hist, int* __restrict__ flag_cnt) {
  const int j = blockIdx.x * 256 + threadIdx.x;
  hist[j] = 0;
  if (j == 0) *flag_cnt = 0;
  const float* e = emb + ((size_t)j << 8);
  ushort* br = Bhi + ((size_t)j << 8);
  double s = 0.0;
  for (int k0 = 0; k0 < 256; k0 += 8) {
    const float4 a = *(const float4*)&e[k0];
    const float4 b = *(const float4*)&e[k0 + 4];
    ushort8v v;
    v[0] = f2bf(a.x); v[1] = f2bf(a.y); v[2] = f2bf(a.z); v[3] = f2bf(a.w);
    v[4] = f2bf(b.x); v[5] = f2bf(b.y); v[6] = f2bf(b.z); v[7] = f2bf(b.w);
    *(ushort8v*)&br[k0] = v;
    s += (double)a.x * (double)a.x;  s += (double)a.y * (double)a.y;
    s += (double)a.z * (double)a.z;  s += (double)a.w * (double)a.w;
    s += (double)b.x * (double)b.x;  s += (double)b.y * (double)b.y;
    s += (double)b.z * (double)b.z;  s += (double)b.w * (double)b.w;
  }
  enormf[j] = (float)s;
}

// ---------- prep: z -> Ahi (bf16, k-XOR-swizzled per row), znf (f64, round once) ----------
// Ahi[m*256 + (k ^ ((m&7)<<3))] = bf16(z[m][k]); 16B-group permutation (bits 3-5 of k).
__global__ __launch_bounds__(256) void vq_prep_z(const float* __restrict__ z,
    ushort* __restrict__ Ahi, float* __restrict__ znf) {
  __shared__ float As[256][68];
  __shared__ double znp[64][4];
  const int t = threadIdx.x;
  const int lane = t & 63, quad = t >> 6;
  const int blk = blockIdx.x;
  const float* zb = z + (((size_t)(blk >> 6)) << 20) + (((size_t)(blk & 63)) << 6);
  {
    const int kr = t >> 4, xc = (t & 15) << 2;
    for (int k0 = 0; k0 < 256; k0 += 16) {
      const int k = k0 + kr;
      *(float4*)&As[k][xc] = *(const float4*)&zb[((size_t)k << 12) + xc];
    }
  }
  __syncthreads();
  {
    double s = 0.0;
    const int kb = quad << 6;
    for (int k = 0; k < 64; ++k) { const double v = (double)As[kb + k][lane]; s += v * v; }
    znp[lane][quad] = s;
  }
  __syncthreads();
  const int m0 = ((blk >> 6) << 12) + ((blk & 63) << 6);
  if (t < 64) znf[m0 + t] = (float)(znp[t][0] + znp[t][1] + znp[t][2] + znp[t][3]);
  const int row = t >> 2;                 // m&7 == row&7 (m0 multiple of 64)
  const int swz = (row & 7) << 3;
  ushort* dst = Ahi + ((size_t)(m0 + row) << 8);
  for (int s = 0; s < 8; ++s) {
    const int k0 = ((t & 3) + (s << 2)) << 3;
    ushort8v v;
#pragma unroll
    for (int i = 0; i < 8; ++i) v[i] = f2bf(As[k0 + i][row]);
    *(ushort8v*)&dst[k0 ^ swz] = v;
  }
}

// ---------- mega: 128 rows x 1024 codes per block ----------
__global__ __launch_bounds__(512, 4) void vq_mega(const ushort* __restrict__ Ahi,
    const ushort* __restrict__ Bhi, const float* __restrict__ znf,
    const float* __restrict__ enormf, float* __restrict__ out,
    int* __restrict__ idxw, int* __restrict__ hist,
    int* __restrict__ flag_cnt, int* __restrict__ flag_rows,
    double* __restrict__ loss_part) {
  __shared__ ushort As[32768];    // 64KB: A tile [128][256], k-swizzled
  __shared__ ushort Bs[2][4096];  // 2 x 8KB: B chunk [128 n][32 k]

  const int t = threadIdx.x;
  const int lane = t & 63;
  const int w = t >> 6;           // 0..7
  const int wr = w >> 1;          // 0..3: 32-row group
  const int wc = w & 1;           // 0..1: 64-col group
  const int g = lane >> 4, cl = lane & 15;
  const int m0 = blockIdx.x << 7;
  float* dmat = out + O_D;

  // prologue: stage A (8 x 16B/thread) + B chunk 0
  {
    const size_t abase = (size_t)m0 << 8;
    const int off = t << 3;
#pragma unroll
    for (int i = 0; i < 8; ++i)
      gload16(Ahi + abase + (i << 12) + off, &As[(i << 12) + off]);
    gload16(Bhi + ((size_t)(t >> 2) << 8) + ((t & 3) << 3), &Bs[0][t << 3]);
  }

  float zn_[2][4];
#pragma unroll
  for (int ai = 0; ai < 2; ++ai)
#pragma unroll
    for (int rg = 0; rg < 4; ++rg)
      zn_[ai][rg] = znf[m0 + (wr << 5) + (ai << 4) + (g << 2) + rg];

  f32x4 acc[2][4];
#pragma unroll
  for (int a = 0; a < 2; ++a)
#pragma unroll
    for (int b = 0; b < 4; ++b) acc[a][b] = (f32x4)(0.0f);
  float run1[8], run2[8]; int runi[8];
#pragma unroll
  for (int r = 0; r < 8; ++r) { run1[r] = 3.0e38f; run2[r] = 3.0e38f; runi[r] = 0; }

  __syncthreads();

  int cur = 0;
  for (int it = 0; it < 64; ++it) {
    const int nt = it >> 3, kch = it & 7;
    if (it < 63) {   // prefetch next B chunk into the other buffer
      const int nit = it + 1;
      const int nnt = nit >> 3, nkch = nit & 7;
      gload16(Bhi + ((size_t)(nnt) << 15) + (nkch << 5) +
                  ((size_t)(t >> 2) << 8) + ((t & 3) << 3),
              &Bs[cur ^ 1][t << 3]);
    }
    {
      const int kb = kch << 5;
      bf16x8 av[2], bv[4];
#pragma unroll
      for (int ai = 0; ai < 2; ++ai) {
        const int row = (wr << 5) + (ai << 4) + cl;
        av[ai] = *(const bf16x8*)&As[(row << 8) + ((kb + (g << 3)) ^ ((cl & 7) << 3))];
      }
#pragma unroll
      for (int bj = 0; bj < 4; ++bj)
        bv[bj] = *(const bf16x8*)&Bs[cur][(((wc << 6) + (bj << 4) + cl) << 5) + (g << 3)];
#pragma unroll
      for (int ai = 0; ai < 2; ++ai)
#pragma unroll
        for (int bj = 0; bj < 4; ++bj)
          acc[ai][bj] = __builtin_amdgcn_mfma_f32_16x16x32_bf16(av[ai], bv[bj], acc[ai][bj], 0, 0, 0);
    }
    if (kch == 7) {   // n-tile nt complete: emit d + fold into running top-2
      float en_[4];
#pragma unroll
      for (int bj = 0; bj < 4; ++bj)
        en_[bj] = enormf[(nt << 7) + (wc << 6) + (bj << 4) + cl];
#pragma unroll
      for (int ai = 0; ai < 2; ++ai) {
#pragma unroll
        for (int bj = 0; bj < 4; ++bj) {
          const int n = (nt << 7) + (wc << 6) + (bj << 4) + cl;
#pragma unroll
          for (int rg = 0; rg < 4; ++rg) {
            const float S = zn_[ai][rg] + en_[bj];
            const float v = S - 2.0f * acc[ai][bj][rg];
            const int m = m0 + (wr << 5) + (ai << 4) + (g << 2) + rg;
            dmat[((size_t)m << 10) + n] = v;
            const int rr = (ai << 2) + rg;
            if (v < run1[rr]) { run2[rr] = run1[rr]; run1[rr] = v; runi[rr] = n; }
            else if (v < run2[rr]) { run2[rr] = v; }
          }
          acc[ai][bj] = (f32x4)(0.0f);
        }
      }
    }
    __syncthreads();
    cur ^= 1;
  }

  // epilogue scratch overlaid on As (all prior As reads complete)
  float*  sd1  = (float*)As;                    // [128][2]
  int*    si1  = (int*)((char*)As + 1024);
  float*  sd2  = (float*)((char*)As + 2048);
  int*    idxs = (int*)((char*)As + 3072);      // [128]
  double* red  = (double*)((char*)As + 3584);   // [128]

  // merge across the 16 cl-lanes sharing each row (np.argmin first-index rule)
#pragma unroll
  for (int rr = 0; rr < 8; ++rr) {
    float a1 = run1[rr], a2 = run2[rr]; int ai1 = runi[rr];
    for (int off = 8; off >= 1; off >>= 1) {
      const float o1 = __shfl_xor(a1, off, 16);
      const int   oi = __shfl_xor(ai1, off, 16);
      const float o2 = __shfl_xor(a2, off, 16);
      const float ns = fminf(fminf(a2, o2), fmaxf(a1, o1));
      if (o1 < a1 || (o1 == a1 && oi < ai1)) { a1 = o1; ai1 = oi; }
      a2 = ns;
    }
    if (cl == 0) {
      const int r = (wr << 5) + ((rr >> 2) << 4) + (g << 2) + (rr & 3);
      sd1[(r << 1) + wc] = a1; si1[(r << 1) + wc] = ai1; sd2[(r << 1) + wc] = a2;
    }
  }
  __syncthreads();
  if (t < 128) {
    const float a1 = sd1[t << 1], b1 = sd1[(t << 1) + 1];
    const int ai1 = si1[t << 1], bi1 = si1[(t << 1) + 1];
    const float a2 = sd2[t << 1], b2 = sd2[(t << 1) + 1];
    float d1, d2; int i1;
    if (b1 < a1 || (b1 == a1 && bi1 < ai1)) { d1 = b1; i1 = bi1; d2 = fminf(a1, b2); }
    else { d1 = a1; i1 = ai1; d2 = fminf(b1, a2); }
    const int m = m0 + t;
    idxw[m] = i1; idxs[t] = i1;
    out[O_IDX + m] = (float)i1;
    atomicAdd(&hist[i1], 1);
    if (d2 - d1 < THR_FLAG) {
      const int p = atomicAdd(flag_cnt, 1);
      flag_rows[p] = m;
    }
    red[t] = (double)d1;     // loss partial: d1 = ||z-e||^2 (+~4e-4 approx; thr ~20)
  }
  __syncthreads();
  for (int off = 64; off > 0; off >>= 1) {
    if (t < off) red[t] += red[t + off];
    __syncthreads();
  }
  if (t == 0) loss_part[blockIdx.x] = red[0];
  __syncthreads();

  // one_hot rows for this block's 128 rows (zeros + single 1)
  float2* ohbase = (float2*)(out + O_OH);
  for (int rr = 0; rr < 16; ++rr) {
    const int r = (w << 4) + rr;
    const int idx = idxs[r];
    float2* row = ohbase + (((size_t)(m0 + r)) << 9);
    const int half = idx >> 1;
#pragma unroll
    for (int i = 0; i < 8; ++i) {
      const int slot = (i << 6) + lane;
      float2 v; v.x = 0.0f; v.y = 0.0f;
      if (slot == half) { if (idx & 1) v.y = 1.0f; else v.x = 1.0f; }
      row[slot] = v;
    }
  }
}

// ---------- candidate-based exact f32-chain refine + output patch ----------
__global__ __launch_bounds__(256) void vq_refine(const float* __restrict__ z,
    const float* __restrict__ emb, const float* __restrict__ znf,
    const float* __restrict__ enormf, const int* __restrict__ flag_cnt,
    const int* __restrict__ flag_rows, int* __restrict__ idxw,
    float* __restrict__ out, int* __restrict__ hist) {
  __shared__ float zrow[256];
  __shared__ float dmin_s[4];
  __shared__ int cand[256];
  __shared__ int ncand_s;
  __shared__ float rv[256];
  __shared__ int ri[256];
  const float* dmat = out + O_D;
  const int t = threadIdx.x;
  const int n = *flag_cnt;
  for (int f = blockIdx.x; f < n; f += gridDim.x) {
    const int m = flag_rows[f];
    __syncthreads();
    if (t == 0) ncand_s = 0;
    zrow[t] = z[(((size_t)(m >> 12)) << 20) + (size_t)(m & 4095) + ((size_t)t << 12)];
    const float* dr = dmat + ((size_t)m << 10);
    const float2 a = *(const float2*)&dr[t << 2];
    const float2 b = *(const float2*)&dr[(t << 2) + 2];
    float dmin = fminf(fminf(a.x, a.y), fminf(b.x, b.y));
    for (int off = 32; off >= 1; off >>= 1) dmin = fminf(dmin, __shfl_xor(dmin, off));
    if ((t & 63) == 0) dmin_s[t >> 6] = dmin;
    __syncthreads();
    dmin = fminf(fminf(dmin_s[0], dmin_s[1]), fminf(dmin_s[2], dmin_s[3]));
    const float lim = dmin + THR_FLAG;
    const float dv[4] = {a.x, a.y, b.x, b.y};
#pragma unroll
    for (int q = 0; q < 4; ++q)
      if (dv[q] <= lim) {
        const int p = atomicAdd(&ncand_s, 1);
        if (p < 256) cand[p] = (t << 2) + q;
      }
    __syncthreads();
    const int nc = min(ncand_s, 256);
    float best = 3.0e38f; int bi = 1 << 30;
    if (t < nc) {
      const int j = cand[t];
      const float* er = emb + ((size_t)j << 8);
      float s = 0.0f;
      for (int k = 0; k < 256; ++k) s = fmaf(zrow[k], er[k], s);
      const float S = znf[m] + enormf[j];
      best = S - 2.0f * s;
      bi = j;
    }
    rv[t] = best; ri[t] = bi;
    __syncthreads();
    for (int off = 128; off > 0; off >>= 1) {
      if (t < off) {
        const float ov = rv[t + off]; const int oi = ri[t + off];
        if (ov < rv[t] || (ov == rv[t] && oi < ri[t])) { rv[t] = ov; ri[t] = oi; }
      }
      __syncthreads();
    }
    if (t == 0) {
      const int nbi = ri[0];
      const int old = idxw[m];
      if (nbi != old) {             // patch idx, one_hot, hist
        idxw[m] = nbi;
        out[O_IDX + m] = (float)nbi;
        out[O_OH + ((size_t)m << 10) + (size_t)old] = 0.0f;
        out[O_OH + ((size_t)m << 10) + (size_t)nbi] = 1.0f;
        atomicAdd(&hist[old], -1);
        atomicAdd(&hist[nbi], 1);
      }
    }
  }
}

// ---------- z_q gather-broadcast (runs after refine; reads final idxw) ----------
__global__ __launch_bounds__(256) void vq_zq(const float* __restrict__ emb,
    const int* __restrict__ idxw, float* __restrict__ zq) {
  __shared__ float E[64][258];
  __shared__ int il[64];
  const int t = threadIdx.x;
  const int blk = blockIdx.x;
  const int base = blk << 6;
  if (t < 64) il[t] = idxw[base + t];
  __syncthreads();
  for (int i = 0; i < 64; ++i) E[i][t] = emb[((size_t)il[i] << 8) + t];
  __syncthreads();
  const int w = t & 63, cg = t >> 6;
  const size_t zbase = (((size_t)(blk >> 6)) << 20) + (((size_t)(blk & 63)) << 6) + (size_t)w;
  for (int ci = 0; ci < 64; ++ci) {
    const int c = (ci << 2) + cg;
    zq[zbase + ((size_t)c << 12)] = E[w][c];
  }
}

__global__ __launch_bounds__(256) void vq_final(const double* __restrict__ loss_part,
    const int* __restrict__ hist, float* __restrict__ out) {
  __shared__ double red[256];
  const int t = threadIdx.x;
  red[t] = loss_part[t] + loss_part[t + 256];
  __syncthreads();
  for (int off = 128; off > 0; off >>= 1) {
    if (t < off) red[t] += red[t + off];
    __syncthreads();
  }
  if (t == 0) out[O_LOSS] = (float)(1.25 * red[0] / 16777216.0);
  __syncthreads();
  double h = 0.0;
  for (int i = t; i < 1024; i += 256) {
    const double p = (double)hist[i] / 65536.0;
    h += p * log(p + 1e-10);
  }
  red[t] = h;
  __syncthreads();
  for (int off = 128; off > 0; off >>= 1) {
    if (t < off) red[t] += red[t + off];
    __syncthreads();
  }
  if (t == 0) out[O_PERP] = (float)exp(-red[0]);
}

extern "C" void kernel_launch(void* const* d_in, const int* in_sizes, int n_in,
                              void* d_out, int out_size, void* d_ws, size_t ws_size,
                              hipStream_t stream) {
  const float* z   = (const float*)d_in[0];
  const float* emb = (const float*)d_in[1];
  float* out = (float*)d_out;
  char* ws = (char*)d_ws;

  float*  enormf    = (float*)(ws + WS_ENORM);
  float*  znf       = (float*)(ws + WS_ZNF);
  int*    idxw      = (int*)(ws + WS_IDX);
  int*    hist      = (int*)(ws + WS_HIST);
  int*    flag_cnt  = (int*)(ws + WS_FCNT);
  int*    flag_rows = (int*)(ws + WS_FROWS);
  double* loss_part = (double*)(ws + WS_LOSS);
  ushort* Ahi       = (ushort*)(ws + WS_AHI);
  ushort* Bhi       = (ushort*)(ws + WS_BHI);

  vq_prep_e<<<4, 256, 0, stream>>>(emb, enormf, Bhi, hist, flag_cnt);
  vq_prep_z<<<1024, 256, 0, stream>>>(z, Ahi, znf);
  vq_mega<<<512, 512, 0, stream>>>(Ahi, Bhi, znf, enormf, out, idxw, hist,
                                   flag_cnt, flag_rows, loss_part);
  vq_refine<<<4096, 256, 0, stream>>>(z, emb, znf, enormf, flag_cnt, flag_rows,
                                      idxw, out, hist);
  vq_zq<<<1024, 256, 0, stream>>>(emb, idxw, out);
  vq_final<<<1, 256, 0, stream>>>(loss_part, hist, out);
}